// Round 1
// 307.769 us; speedup vs baseline: 1.0265x; 1.0265x over previous
//
#include <hip/hip_runtime.h>
#include <hip/hip_bf16.h>
#include <cstdint>

// ---------------------------------------------------------------------------
// LinearMultiHeadAttention: B=4, S=4096, D_MODEL=1024, H=16, Dk=64
// Gram-path:
//   G[b]  = x[b]^T x[b]     (SYMMETRIC: upper-triangle tiles only, split-K=4)
//   H[b]  = Wk @ G[b]
//   kv[b,h] = H_h @ Wv_h^T
//   E_t[b][j][hd] = scale*sum_e kv*Wo
//   F[b]  = E_t[b] @ Wq
//   out   = x @ F[b]^T
// R7: final GEMM (out = x@F^T, the 52us/26%-MfmaUtil dispatch) moved to the
// 256x256 8-phase template (T2 swizzle + T3/T4 counted-vmcnt + T5 setprio):
//   - BM=BN=256, BK=64, 512 thr (8 waves 2Mx4N), 128KiB LDS double-buffer
//   - per phase: ds_read reg subtile (12 at p0 / 4 else) + 1 half-tile
//     global_load_lds prefetch, barrier, lgkmcnt(0), 16 MFMA @prio1, barrier
//   - vmcnt(6) once per K-tile (3 half-tiles in flight across barriers);
//     vmcnt(0) only at kt==NT-2 to drain the tail
//   - LDS XOR swizzle byte^=((row&7)<<4), applied on the READ addr and as
//     inverse-swizzled GLOBAL source (gld_lds dest stays linear, rule 21)
// ---------------------------------------------------------------------------

typedef __bf16 bf16x8 __attribute__((ext_vector_type(8)));
typedef float f32x4 __attribute__((ext_vector_type(4)));
typedef unsigned short ushort_t;

__device__ inline void gld_lds16(const void* g, void* l) {
    __builtin_amdgcn_global_load_lds(
        (const __attribute__((address_space(1))) unsigned int*)g,
        (__attribute__((address_space(3))) unsigned int*)l,
        16, 0, 0);
}

__device__ inline ushort_t f2bf(float f) {
    uint32_t u = __float_as_uint(f);
    uint32_t r = (u + 0x7fffu + ((u >> 16) & 1u)) >> 16;
    return (ushort_t)r;
}
__device__ inline float bf2f(ushort_t u) {
    return __uint_as_float((uint32_t)u << 16);
}

// ---------------------------------------------------------------------------
// Generic C = A @ B^T. 128x128 tile, BK=32, XOR-swizzled LDS (conflict-free).
// (kept for H = Wk@G and F = Et@Wq, where 256^2 tiles would underfill the grid)
// ---------------------------------------------------------------------------
template <typename OutT>
__global__ __launch_bounds__(256, 2)
void gemm_bt(const ushort_t* __restrict__ A, int lda, long strideA,
             const ushort_t* __restrict__ B, int ldb, long strideB,
             OutT* __restrict__ C0, int ldc0, long strideC0, int K)
{
    __shared__ ushort_t lA[128 * 32];
    __shared__ ushort_t lB[128 * 32];

    const int t    = threadIdx.x;
    const int lane = t & 63;
    const int wid  = t >> 6;
    const int z    = blockIdx.z;

    A += (size_t)z * strideA;
    B += (size_t)z * strideB;

    const int m0 = blockIdx.x * 128;
    const int n0 = blockIdx.y * 128;

    const int wm = (wid >> 1) * 64;
    const int wn = (wid & 1) * 64;
    const int mr = lane & 15;
    const int q4 = lane >> 4;

    const int row_a = t >> 2;
    const int seg   = ((t & 3) ^ ((t >> 3) & 3)) * 8;
    const int csw   = (q4 ^ ((mr >> 1) & 3)) * 16;

    f32x4 acc[4][4] = {};

    for (int k0 = 0; k0 < K; k0 += 32) {
        __syncthreads();
        gld_lds16(A + (size_t)(m0 + row_a) * lda + k0 + seg,      (char*)lA + wid * 1024);
        gld_lds16(A + (size_t)(m0 + 64 + row_a) * lda + k0 + seg, (char*)lA + 4096 + wid * 1024);
        gld_lds16(B + (size_t)(n0 + row_a) * ldb + k0 + seg,      (char*)lB + wid * 1024);
        gld_lds16(B + (size_t)(n0 + 64 + row_a) * ldb + k0 + seg, (char*)lB + 4096 + wid * 1024);
        __syncthreads();

        bf16x8 af[4], bf[4];
#pragma unroll
        for (int i = 0; i < 4; ++i)
            af[i] = *(const bf16x8*)((const char*)lA + (wm + i * 16 + mr) * 64 + csw);
#pragma unroll
        for (int j = 0; j < 4; ++j)
            bf[j] = *(const bf16x8*)((const char*)lB + (wn + j * 16 + mr) * 64 + csw);
#pragma unroll
        for (int i = 0; i < 4; ++i)
#pragma unroll
            for (int j = 0; j < 4; ++j)
                acc[i][j] = __builtin_amdgcn_mfma_f32_16x16x32_bf16(af[i], bf[j], acc[i][j], 0, 0, 0);
    }

    OutT* Cw = C0 + (size_t)z * strideC0;
#pragma unroll
    for (int i = 0; i < 4; ++i) {
        const int rbase = m0 + wm + i * 16 + q4 * 4;
#pragma unroll
        for (int j = 0; j < 4; ++j) {
            const int col = n0 + wn + j * 16 + mr;
#pragma unroll
            for (int r = 0; r < 4; ++r) {
                const float v = acc[i][j][r];
                const size_t off = (size_t)(rbase + r) * ldc0 + col;
                if constexpr (sizeof(OutT) == 2) Cw[off] = f2bf(v);
                else                             Cw[off] = v;
            }
        }
    }
}

// ---------------------------------------------------------------------------
// C = A @ B^T, fp32 out. 256x256 tile, BK=64, 8-phase schedule (m201-style).
// 512 threads = 8 waves (2M x 4N), per-wave 128x64 output, acc[8][4].
// LDS 128 KiB: A dbuf [2][2half][128][64], B dbuf same, at +65536.
// Swizzle: logical (row, colByte) lives at physical row*128 + (colByte ^
// ((row&7)<<4)). gld_lds writes physical-linear, so the GLOBAL source for a
// physical chunk is computed with the same (involutive) XOR.
// Stage stream: prologue kt0{B0,B1,A0,A1}+kt1{B0,B1,A0}, vmcnt(6);
// S(kt,0)=(kt+1).A1, S(kt,1)=(kt+2).B0, S(kt,2)=(kt+2).B1, S(kt,3)=(kt+2).A0.
// Checkpoint vmcnt(6) at end of each kt leaves exactly S(kt,1..3) in flight;
// kt+1 is always fully landed. vmcnt(0) at kt==NT-2 drains the tail.
// ---------------------------------------------------------------------------
__global__ __launch_bounds__(512, 2)
void gemm256_bt(const ushort_t* __restrict__ A, int lda, long strideA,
                const ushort_t* __restrict__ B, int ldb, long strideB,
                float* __restrict__ C, int ldc, long strideC, int K)
{
    __shared__ char lds[131072];

    const int t    = threadIdx.x;
    const int lane = t & 63;
    const int wid  = t >> 6;       // 0..7
    const int z    = blockIdx.z;

    A += (size_t)z * strideA;
    B += (size_t)z * strideB;

    const int m0 = blockIdx.x * 256;
    const int n0 = blockIdx.y * 256;

    const int wm = wid >> 2;       // 0..1  (row half)
    const int wn = wid & 3;        // 0..3  (64-col slice)
    const int mr = lane & 15;
    const int q4 = lane >> 4;      // 0..3

    const int NT = K >> 6;         // 64-wide K-tiles

    // --- staging geometry (per thread): physical chunk = t*16 within 8KB,
    // two chunks (rows +0 / +64). Inverse-swizzled global column:
    const int srow = t >> 3;                                    // 0..63
    const int scol = ((t & 7) << 3) ^ (((t >> 3) & 7) << 3);    // elements

    auto stage_half = [&](const ushort_t* __restrict__ src, int ld, int org,
                          int h, int tgt, int bsel) {
        if (tgt >= NT) return;
        char* base = lds + bsel + ((tgt & 1) << 15) + (h << 14) + wid * 1024;
        const ushort_t* g = src + (size_t)(org + h * 128 + srow) * ld + tgt * 64 + scol;
        gld_lds16(g, base);                          // rows 0..63 of half
        gld_lds16(g + ((size_t)ld << 6), base + 8192); // rows 64..127
    };
    // unit ids: 0=B.h0 1=B.h1 2=A.h0 3=A.h1
    auto stage_unit = [&](int u, int tgt) {
        if (u < 2) stage_half(B, ldb, n0, u,     tgt, 65536);
        else       stage_half(A, lda, m0, u - 2, tgt, 0);
    };

    // --- prologue: kt0 full + kt1 {B0,B1,A0}; keep 3 units in flight
    stage_unit(0, 0); stage_unit(1, 0); stage_unit(2, 0); stage_unit(3, 0);
    stage_unit(0, 1); stage_unit(1, 1); stage_unit(2, 1);
    asm volatile("s_waitcnt vmcnt(6)" ::: "memory");
    __builtin_amdgcn_s_barrier();

    f32x4 acc[8][4] = {};

    for (int kt = 0; kt < NT; ++kt) {
        const char* aBuf = lds + ((kt & 1) << 15) + (wm << 14);
        const char* bBuf = lds + 65536 + ((kt & 1) << 15) + ((wn >> 1) << 14);
        const int cb = (wn & 1) << 6;

        bf16x8 bB[4][2];
#pragma unroll
        for (int p = 0; p < 4; ++p) {
            // ---- ds_read register subtile ----
            bf16x8 aA[2][2];
#pragma unroll
            for (int s = 0; s < 2; ++s) {
                const int lr = (2 * p + s) * 16 + mr;
                const int kx = (lr & 7) << 4;
#pragma unroll
                for (int ks = 0; ks < 2; ++ks)
                    aA[s][ks] = *(const bf16x8*)(aBuf + lr * 128 + ((ks * 64 + q4 * 16) ^ kx));
            }
            if (p == 0) {
#pragma unroll
                for (int j = 0; j < 4; ++j) {
                    const int c  = cb + j * 16 + mr;
                    const int kx = (c & 7) << 4;
#pragma unroll
                    for (int ks = 0; ks < 2; ++ks)
                        bB[j][ks] = *(const bf16x8*)(bBuf + c * 128 + ((ks * 64 + q4 * 16) ^ kx));
                }
            }
            // ---- stage-issue 1 half-tile (prefetch) ----
            if      (p == 0) stage_unit(3, kt + 1);   // (kt+1).A1 -> other buf
            else if (p == 1) stage_unit(0, kt + 2);   // (kt+2).B0 (dead since p0)
            else if (p == 2) stage_unit(1, kt + 2);   // (kt+2).B1
            else             stage_unit(2, kt + 2);   // (kt+2).A0 (after last A0 reads)

            __builtin_amdgcn_s_barrier();
            asm volatile("s_waitcnt lgkmcnt(0)" ::: "memory");
            __builtin_amdgcn_sched_barrier(0);

            __builtin_amdgcn_s_setprio(1);
#pragma unroll
            for (int s = 0; s < 2; ++s)
#pragma unroll
                for (int j = 0; j < 4; ++j)
#pragma unroll
                    for (int ks = 0; ks < 2; ++ks)
                        acc[2 * p + s][j] = __builtin_amdgcn_mfma_f32_16x16x32_bf16(
                            aA[s][ks], bB[j][ks], acc[2 * p + s][j], 0, 0, 0);
            __builtin_amdgcn_s_setprio(0);
            __builtin_amdgcn_sched_barrier(0);

            if (p == 3) {
                if (kt == NT - 2)     asm volatile("s_waitcnt vmcnt(0)" ::: "memory");
                else if (kt < NT - 2) asm volatile("s_waitcnt vmcnt(6)" ::: "memory");
            }
            __builtin_amdgcn_s_barrier();
        }
    }

    float* Cw = C + (size_t)z * strideC;
#pragma unroll
    for (int i = 0; i < 8; ++i) {
        const int row = m0 + wm * 128 + i * 16 + q4 * 4;
#pragma unroll
        for (int j = 0; j < 4; ++j) {
            const int col = n0 + wn * 64 + j * 16 + mr;
#pragma unroll
            for (int r = 0; r < 4; ++r)
                Cw[(size_t)(row + r) * ldc + col] = acc[i][j][r];
        }
    }
}

// ---------------------------------------------------------------------------
// Gram GEMM: Gp[z] partial of x[b]^T x[b], upper-triangle 128-tiles only.
// grid (16 z fastest -> XCD round-robin, 36 triangle tiles). A = B = xbT.
// z = b*4+ks: columns b*4096 + ks*1024 of xbT [1024][16384].
// ---------------------------------------------------------------------------
__global__ __launch_bounds__(256, 2)
void gemm_gram(const ushort_t* __restrict__ X, ushort_t* __restrict__ Gp)
{
    __shared__ ushort_t lA[128 * 32];
    __shared__ ushort_t lB[128 * 32];

    const int t    = threadIdx.x;
    const int lane = t & 63;
    const int wid  = t >> 6;

    const int z  = blockIdx.x;
    const int bb = z >> 2, ks = z & 3;

    // triangle tile map: row ti has 8-ti tiles (ti<=tj)
    int ti = 0, rem = blockIdx.y;
    while (rem >= 8 - ti) { rem -= 8 - ti; ++ti; }
    const int tj = ti + rem;
    const int m0 = ti * 128;
    const int n0 = tj * 128;

    const ushort_t* A = X + (size_t)bb * 4096 + (size_t)ks * 1024;

    const int wm = (wid >> 1) * 64;
    const int wn = (wid & 1) * 64;
    const int mr = lane & 15;
    const int q4 = lane >> 4;

    const int row_a = t >> 2;
    const int seg   = ((t & 3) ^ ((t >> 3) & 3)) * 8;
    const int csw   = (q4 ^ ((mr >> 1) & 3)) * 16;

    f32x4 acc[4][4] = {};

    for (int k0 = 0; k0 < 1024; k0 += 32) {
        __syncthreads();
        gld_lds16(A + (size_t)(m0 + row_a) * 16384 + k0 + seg,      (char*)lA + wid * 1024);
        gld_lds16(A + (size_t)(m0 + 64 + row_a) * 16384 + k0 + seg, (char*)lA + 4096 + wid * 1024);
        gld_lds16(A + (size_t)(n0 + row_a) * 16384 + k0 + seg,      (char*)lB + wid * 1024);
        gld_lds16(A + (size_t)(n0 + 64 + row_a) * 16384 + k0 + seg, (char*)lB + 4096 + wid * 1024);
        __syncthreads();

        bf16x8 af[4], bf[4];
#pragma unroll
        for (int i = 0; i < 4; ++i)
            af[i] = *(const bf16x8*)((const char*)lA + (wm + i * 16 + mr) * 64 + csw);
#pragma unroll
        for (int j = 0; j < 4; ++j)
            bf[j] = *(const bf16x8*)((const char*)lB + (wn + j * 16 + mr) * 64 + csw);
#pragma unroll
        for (int i = 0; i < 4; ++i)
#pragma unroll
            for (int j = 0; j < 4; ++j)
                acc[i][j] = __builtin_amdgcn_mfma_f32_16x16x32_bf16(af[i], bf[j], acc[i][j], 0, 0, 0);
    }

    ushort_t* Cw = Gp + ((size_t)z << 20);
#pragma unroll
    for (int i = 0; i < 4; ++i) {
        const int rbase = m0 + wm + i * 16 + q4 * 4;
#pragma unroll
        for (int j = 0; j < 4; ++j) {
            const int col = n0 + wn + j * 16 + mr;
#pragma unroll
            for (int r = 0; r < 4; ++r)
                Cw[(size_t)(rbase + r) * 1024 + col] = f2bf(acc[i][j][r]);
        }
    }
}

// ---------------------------------------------------------------------------
// reduce_g_t: G[b][tr*64+r][tc*64+c] = sum_ks Gp[b*4+ks] at source 64-tile
// (sr,sc)=(min,max) -- inside computed upper 128-triangle since
// sr<=sc => sr>>1 <= sc>>1. Lower tiles transpose through LDS (pitch 65).
// grid (256 tiles: tr=bx>>4, tc=bx&15; 4 b), 256 threads.
// ---------------------------------------------------------------------------
__global__ __launch_bounds__(256)
void reduce_g_t(const ushort_t* __restrict__ Gp, ushort_t* __restrict__ G)
{
    __shared__ float acc[64 * 65];

    const int t  = threadIdx.x;
    const int b  = blockIdx.y;
    const int tr = blockIdx.x >> 4, tc = blockIdx.x & 15;
    const int sr = (tr <= tc) ? tr : tc;
    const int sc = (tr <= tc) ? tc : tr;
    const bool flip = tr > tc;

#pragma unroll
    for (int p = 0; p < 4; ++p) {
        const int idx = p * 256 + t;             // ushort4 index 0..1023
        const int r = idx >> 4, c = (idx & 15) * 4;
        float a0 = 0.f, a1 = 0.f, a2 = 0.f, a3 = 0.f;
#pragma unroll
        for (int ksl = 0; ksl < 4; ++ksl) {
            const ushort4 u = *(const ushort4*)&Gp[((size_t)(b * 4 + ksl) << 20)
                                                   + (size_t)(sr * 64 + r) * 1024 + sc * 64 + c];
            a0 += bf2f(u.x); a1 += bf2f(u.y); a2 += bf2f(u.z); a3 += bf2f(u.w);
        }
        acc[r * 65 + c + 0] = a0;
        acc[r * 65 + c + 1] = a1;
        acc[r * 65 + c + 2] = a2;
        acc[r * 65 + c + 3] = a3;
    }
    __syncthreads();

#pragma unroll
    for (int p = 0; p < 4; ++p) {
        const int idx = p * 256 + t;
        const int r = idx >> 4, c = (idx & 15) * 4;
        float v0, v1, v2, v3;
        if (flip) {
            v0 = acc[(c + 0) * 65 + r];
            v1 = acc[(c + 1) * 65 + r];
            v2 = acc[(c + 2) * 65 + r];
            v3 = acc[(c + 3) * 65 + r];
        } else {
            v0 = acc[r * 65 + c + 0];
            v1 = acc[r * 65 + c + 1];
            v2 = acc[r * 65 + c + 2];
            v3 = acc[r * 65 + c + 3];
        }
        ushort4 o;
        o.x = f2bf(v0); o.y = f2bf(v1); o.z = f2bf(v2); o.w = f2bf(v3);
        *(ushort4*)&G[((size_t)b << 20) + (size_t)(tr * 64 + r) * 1024 + tc * 64 + c] = o;
    }
}

// ---------------------------------------------------------------------------
// cast x fp32 [16384][1024] -> xb bf16 + xbT bf16 [1024][16384]
// ---------------------------------------------------------------------------
__global__ __launch_bounds__(256)
void cast_x_t(const float* __restrict__ x, ushort_t* __restrict__ xb,
              ushort_t* __restrict__ xbT)
{
    __shared__ ushort_t lt[64 * 66];
    const int t  = threadIdx.x;
    const int s0 = blockIdx.x * 64;
    const int i0 = blockIdx.y * 64;

#pragma unroll
    for (int c = 0; c < 4; ++c) {
        const int idx = c * 256 + t;
        const int r = idx >> 4, c4 = (idx & 15) * 4;
        const float4 f = *(const float4*)&x[(size_t)(s0 + r) * 1024 + i0 + c4];
        ushort4 o;
        o.x = f2bf(f.x); o.y = f2bf(f.y); o.z = f2bf(f.z); o.w = f2bf(f.w);
        *(ushort4*)&xb[(size_t)(s0 + r) * 1024 + i0 + c4] = o;
        *(uint32_t*)&lt[r * 66 + c4]     = (uint32_t)o.x | ((uint32_t)o.y << 16);
        *(uint32_t*)&lt[r * 66 + c4 + 2] = (uint32_t)o.z | ((uint32_t)o.w << 16);
    }
    __syncthreads();
#pragma unroll
    for (int c = 0; c < 4; ++c) {
        const int idx = c * 256 + t;
        const int ri = idx >> 4, s4 = (idx & 15) * 4;
        ushort4 o;
        o.x = lt[(s4 + 0) * 66 + ri];
        o.y = lt[(s4 + 1) * 66 + ri];
        o.z = lt[(s4 + 2) * 66 + ri];
        o.w = lt[(s4 + 3) * 66 + ri];
        *(ushort4*)&xbT[(size_t)(i0 + ri) * 16384 + s0 + s4] = o;
    }
}

// ---------------------------------------------------------------------------
// cast+transpose Wq fp32 -> wqT bf16
// ---------------------------------------------------------------------------
__global__ __launch_bounds__(256)
void cast_wt(const float* __restrict__ W, ushort_t* __restrict__ WT)
{
    __shared__ ushort_t lt[64 * 66];
    const int t  = threadIdx.x;
    const int r0 = blockIdx.x * 64;
    const int c0 = blockIdx.y * 64;

#pragma unroll
    for (int c = 0; c < 4; ++c) {
        const int idx = c * 256 + t;
        const int r = idx >> 4, c4 = (idx & 15) * 4;
        const float4 f = *(const float4*)&W[(size_t)(r0 + r) * 1024 + c0 + c4];
        ushort4 o;
        o.x = f2bf(f.x); o.y = f2bf(f.y); o.z = f2bf(f.z); o.w = f2bf(f.w);
        *(uint32_t*)&lt[r * 66 + c4]     = (uint32_t)o.x | ((uint32_t)o.y << 16);
        *(uint32_t*)&lt[r * 66 + c4 + 2] = (uint32_t)o.z | ((uint32_t)o.w << 16);
    }
    __syncthreads();
#pragma unroll
    for (int c = 0; c < 4; ++c) {
        const int idx = c * 256 + t;
        const int ri = idx >> 4, s4 = (idx & 15) * 4;
        ushort4 o;
        o.x = lt[(s4 + 0) * 66 + ri];
        o.y = lt[(s4 + 1) * 66 + ri];
        o.z = lt[(s4 + 2) * 66 + ri];
        o.w = lt[(s4 + 3) * 66 + ri];
        *(ushort4*)&WT[(size_t)(c0 + ri) * 1024 + r0 + s4] = o;
    }
}

// ---------------------------------------------------------------------------
// plain cast Wk/Wv fp32 -> bf16
// ---------------------------------------------------------------------------
__global__ __launch_bounds__(256)
void cast_w2(const float* __restrict__ a, const float* __restrict__ b,
             ushort_t* __restrict__ out)
{
    const float* src = (blockIdx.y == 0) ? a : b;
    const int i = (blockIdx.x * 256 + threadIdx.x) * 4;
    const float4 f = *(const float4*)&src[i];
    ushort4 o;
    o.x = f2bf(f.x); o.y = f2bf(f.y); o.z = f2bf(f.z); o.w = f2bf(f.w);
    *(ushort4*)&out[(size_t)blockIdx.y * 1048576 + i] = o;
}

// ---------------------------------------------------------------------------
// kv partials: KVp[is][bh][d][e] = sum_{i-slice} H[b][h64+d][i]*Wv[h64+e][i]
// ---------------------------------------------------------------------------
__global__ __launch_bounds__(256)
void kvblk(const ushort_t* __restrict__ H, const ushort_t* __restrict__ Wv,
           float* __restrict__ KVp)
{
    __shared__ ushort_t sH[64 * 132];
    __shared__ ushort_t sV[64 * 132];

    const int t  = threadIdx.x;
    const int is = blockIdx.x;
    const int bh = blockIdx.y;
    const int b  = bh >> 4, h = bh & 15;

    const ushort_t* Hp = H + ((size_t)b << 20) + (size_t)(h * 64) * 1024 + is * 128;
    const ushort_t* Vp = Wv + (size_t)(h * 64) * 1024 + is * 128;

#pragma unroll
    for (int i2 = 0; i2 < 8; ++i2) {
        const int ci = i2 * 256 + t;
        const int r = ci >> 5, c = (ci & 31) * 4;
        *(uint2*)&sH[r * 132 + c] = *(const uint2*)&Hp[(size_t)r * 1024 + c];
        *(uint2*)&sV[r * 132 + c] = *(const uint2*)&Vp[(size_t)r * 1024 + c];
    }
    __syncthreads();

    const int d0 = (t >> 4) * 4;
    const int e0 = (t & 15) * 4;
    float acc[4][4] = {};

#pragma unroll 2
    for (int i4 = 0; i4 < 128; i4 += 4) {
        uint2 hu[4], vu[4];
#pragma unroll
        for (int j = 0; j < 4; ++j) {
            hu[j] = *(const uint2*)&sH[(d0 + j) * 132 + i4];
            vu[j] = *(const uint2*)&sV[(e0 + j) * 132 + i4];
        }
        float hf[4][4], vf[4][4];
#pragma unroll
        for (int j = 0; j < 4; ++j) {
            hf[j][0] = __uint_as_float(hu[j].x << 16);
            hf[j][1] = __uint_as_float(hu[j].x & 0xffff0000u);
            hf[j][2] = __uint_as_float(hu[j].y << 16);
            hf[j][3] = __uint_as_float(hu[j].y & 0xffff0000u);
            vf[j][0] = __uint_as_float(vu[j].x << 16);
            vf[j][1] = __uint_as_float(vu[j].x & 0xffff0000u);
            vf[j][2] = __uint_as_float(vu[j].y << 16);
            vf[j][3] = __uint_as_float(vu[j].y & 0xffff0000u);
        }
#pragma unroll
        for (int ii = 0; ii < 4; ++ii)
#pragma unroll
            for (int di = 0; di < 4; ++di)
#pragma unroll
                for (int ej = 0; ej < 4; ++ej)
                    acc[di][ej] += hf[di][ii] * vf[ej][ii];
    }

    float* outp = KVp + ((size_t)(is * 64 + bh)) * 4096;
#pragma unroll
    for (int i = 0; i < 4; ++i) {
        float4 o; o.x = acc[i][0]; o.y = acc[i][1]; o.z = acc[i][2]; o.w = acc[i][3];
        *(float4*)&outp[(d0 + i) * 64 + e0] = o;
    }
}

// ---------------------------------------------------------------------------
__global__ __launch_bounds__(256)
void reduce_kv8(const float4* __restrict__ in, float4* __restrict__ out)
{
    const int i = blockIdx.x * 256 + threadIdx.x;
    float4 a = in[i];
#pragma unroll
    for (int s = 1; s < 8; ++s) {
        const float4 b = in[s * 65536 + i];
        a.x += b.x; a.y += b.y; a.z += b.z; a.w += b.w;
    }
    out[i] = a;
}

// ---------------------------------------------------------------------------
// E_t[b][j][h*64+d] = scale * sum_e kv[b,h,d,e] * W_o[j, h*64+e]
// ---------------------------------------------------------------------------
__global__ __launch_bounds__(256)
void make_E(const float* __restrict__ KV, const float* __restrict__ Wo,
            ushort_t* __restrict__ Et)
{
    __shared__ float skv[64 * 65];
    __shared__ float swo[64 * 65];

    const int t  = threadIdx.x;
    const int bh = blockIdx.y;
    const int b  = bh >> 4, h = bh & 15;
    const int j0 = blockIdx.x * 64;

    const float* kvp = KV + (size_t)bh * 4096;
#pragma unroll
    for (int i = 0; i < 4; ++i) {
        const int idx = t + i * 256;
        const int r = idx >> 4, c = (idx & 15) * 4;
        const float4 f = *(const float4*)&kvp[r * 64 + c];
        skv[r * 65 + c + 0] = f.x;
        skv[r * 65 + c + 1] = f.y;
        skv[r * 65 + c + 2] = f.z;
        skv[r * 65 + c + 3] = f.w;
        const float4 g = *(const float4*)&Wo[(size_t)(j0 + r) * 1024 + h * 64 + c];
        swo[r * 65 + c + 0] = g.x;
        swo[r * 65 + c + 1] = g.y;
        swo[r * 65 + c + 2] = g.z;
        swo[r * 65 + c + 3] = g.w;
    }
    __syncthreads();

    const int d0 = (t & 15) * 4;
#pragma unroll
    for (int pass = 0; pass < 4; ++pass) {
        const int jloc = (t >> 4) + pass * 16;
        float s0 = 0.f, s1 = 0.f, s2 = 0.f, s3 = 0.f;
        const float* wrow = &swo[jloc * 65];
#pragma unroll 8
        for (int e = 0; e < 64; ++e) {
            const float w = wrow[e];
            s0 += skv[(d0 + 0) * 65 + e] * w;
            s1 += skv[(d0 + 1) * 65 + e] * w;
            s2 += skv[(d0 + 2) * 65 + e] * w;
            s3 += skv[(d0 + 3) * 65 + e] * w;
        }
        ushort4 o;
        o.x = f2bf(s0 * 0.125f);
        o.y = f2bf(s1 * 0.125f);
        o.z = f2bf(s2 * 0.125f);
        o.w = f2bf(s3 * 0.125f);
        *(ushort4*)&Et[((size_t)b * 1024 + j0 + jloc) * 1024 + h * 64 + d0] = o;
    }
}

// ---------------------------------------------------------------------------

extern "C" void kernel_launch(void* const* d_in, const int* in_sizes, int n_in,
                              void* d_out, int out_size, void* d_ws, size_t ws_size,
                              hipStream_t stream)
{
    const float* x  = (const float*)d_in[0];
    const float* Wq = (const float*)d_in[1];
    const float* Wk = (const float*)d_in[2];
    const float* Wv = (const float*)d_in[3];
    const float* Wo = (const float*)d_in[4];
    float* out = (float*)d_out;

    const int B = 4, S = 4096, D = 1024;
    const long MB1 = 1048576;

    char* ws = (char*)d_ws;
    size_t off = 0;
    auto alloc = [&](size_t bytes) -> void* {
        void* p = ws + off;
        off += (bytes + 255) & ~(size_t)255;
        return p;
    };
    ushort_t* xb   = (ushort_t*)alloc((size_t)B * S * D * 2);      // 33.5 MB
    ushort_t* xbT  = (ushort_t*)alloc((size_t)D * B * S * 2);      // 33.5 MB
    ushort_t* wkv  = (ushort_t*)alloc((size_t)2 * D * D * 2);      // wk | wv
    ushort_t* wqT  = (ushort_t*)alloc((size_t)D * D * 2);
    ushort_t* Gb   = (ushort_t*)alloc((size_t)B * D * D * 2);      // 8.4 MB
    float*    kvp  = (float*)alloc((size_t)8 * 64 * 4096 * 4);     // 8.4 MB
    float*    kvr  = (float*)alloc((size_t)64 * 4096 * 4);         // 1 MB
    ushort_t* Fb   = (ushort_t*)alloc((size_t)B * D * D * 2);      // 8.4 MB (own slab!)
    char*     R1   = (char*)alloc((size_t)16 * MB1 * 2);           // 33.5 MB shared
    ushort_t* Gp = (ushort_t*)R1;                    // [16][1M] bf16 partials
    ushort_t* Hb = (ushort_t*)R1;                    // [4][1M] (Gp[0..7] dead after reduce)
    ushort_t* Et = (ushort_t*)(R1 + 8 * MB1 * 2);    // [4][1M] (Gp[8..15] dead after reduce)
    ushort_t* wkb = wkv;
    ushort_t* wvb = wkv + MB1;

    // casts
    cast_x_t<<<dim3(256, 16), dim3(256), 0, stream>>>(x, xb, xbT);
    cast_w2<<<dim3(1024, 2), dim3(256), 0, stream>>>(Wk, Wv, wkv);
    cast_wt<<<dim3(16, 16), dim3(256), 0, stream>>>(Wq, wqT);

    // G[b] = x^T x, symmetric: 36 upper-triangle 128-tiles, split-K=4, z fastest
    gemm_gram<<<dim3(16, 36), dim3(256), 0, stream>>>(xbT, Gp);
    reduce_g_t<<<dim3(256, 4), dim3(256), 0, stream>>>(Gp, Gb);

    // H[b] = Wk @ G[b]  (G symmetric -> use as B directly)
    gemm_bt<ushort_t><<<dim3(8, 8, 4), dim3(256), 0, stream>>>(
        wkb, D, 0, Gb, D, MB1, Hb, D, MB1, D);

    // kv[b,h] = H_h @ Wv_h^T (i-split 8) + reduce
    kvblk<<<dim3(8, 64), dim3(256), 0, stream>>>(Hb, wvb, kvp);
    reduce_kv8<<<dim3(256), dim3(256), 0, stream>>>((const float4*)kvp, (float4*)kvr);

    // E_t
    make_E<<<dim3(16, 64), dim3(256), 0, stream>>>(kvr, Wo, Et);

    // F[b] = E_t[b] @ Wq
    gemm_bt<ushort_t><<<dim3(8, 8, 4), dim3(256), 0, stream>>>(
        Et, D, MB1, wqT, D, 0, Fb, D, (long)D * D, D);

    // out[b] = x[b] @ F[b]^T -> fp32, 256^2 8-phase (R7)
    gemm256_bt<<<dim3(16, 4, 4), dim3(512), 0, stream>>>(
        xb, D, (long)S * D, Fb, D, (long)D * D, out, D, (long)S * D, D);
}

// Round 2
// 302.914 us; speedup vs baseline: 1.0429x; 1.0160x over previous
//
#include <hip/hip_runtime.h>
#include <hip/hip_bf16.h>
#include <cstdint>

// ---------------------------------------------------------------------------
// LinearMultiHeadAttention: B=4, S=4096, D_MODEL=1024, H=16, Dk=64
// Gram-path:
//   G[b]  = x[b]^T x[b]     (SYMMETRIC: upper-triangle tiles only, split-K=4)
//   H[b]  = Wk @ G[b]
//   kv[b,h] = H_h @ Wv_h^T
//   E_t[b][j][hd] = scale*sum_e kv*Wo
//   F[b]  = E_t[b] @ Wq
//   out   = x @ F[b]^T
// R8 vs R7:
//   - gemm256_bt: ds_reads software-pipelined one phase ahead (aA double-set,
//     bB(kt+1) read at p3 after the vmcnt checkpoint) -> lgkmcnt(0) waits on
//     reads issued a full MFMA-cluster earlier. Epilogue routed through LDS
//     (dead after K-loop) -> global_store_dwordx4, 1KiB contiguous per instr.
//   - H = Wk@G and F = Et@Wq moved to 128x64-tile gemm_bt_n64, grid 512
//     (2 blocks/CU) so barrier drains overlap across blocks (they were 256
//     blocks = 1/CU = zero overlap).
// ---------------------------------------------------------------------------

typedef __bf16 bf16x8 __attribute__((ext_vector_type(8)));
typedef float f32x4 __attribute__((ext_vector_type(4)));
typedef unsigned short ushort_t;

__device__ inline void gld_lds16(const void* g, void* l) {
    __builtin_amdgcn_global_load_lds(
        (const __attribute__((address_space(1))) unsigned int*)g,
        (__attribute__((address_space(3))) unsigned int*)l,
        16, 0, 0);
}

__device__ inline ushort_t f2bf(float f) {
    uint32_t u = __float_as_uint(f);
    uint32_t r = (u + 0x7fffu + ((u >> 16) & 1u)) >> 16;
    return (ushort_t)r;
}
__device__ inline float bf2f(ushort_t u) {
    return __uint_as_float((uint32_t)u << 16);
}

// ---------------------------------------------------------------------------
// C = A @ B^T. 128x64 tile, BK=32, XOR-swizzled LDS. 256 thr = 4 waves (2Mx2N),
// per-wave 64x32 out. Small tile -> 512 blocks for 1024x1024 GEMMs -> 2/CU
// resident, cross-block overlap hides the per-iter barrier drain.
// ---------------------------------------------------------------------------
template <typename OutT>
__global__ __launch_bounds__(256, 4)
void gemm_bt_n64(const ushort_t* __restrict__ A, int lda, long strideA,
                 const ushort_t* __restrict__ B, int ldb, long strideB,
                 OutT* __restrict__ C0, int ldc0, long strideC0, int K)
{
    __shared__ ushort_t lA[128 * 32];
    __shared__ ushort_t lB[64 * 32];

    const int t    = threadIdx.x;
    const int lane = t & 63;
    const int wid  = t >> 6;          // 0..3
    const int z    = blockIdx.z;

    A += (size_t)z * strideA;
    B += (size_t)z * strideB;

    const int m0 = blockIdx.x * 128;
    const int n0 = blockIdx.y * 64;

    const int wm = (wid >> 1) * 64;   // 0,64
    const int wn = (wid & 1) * 32;    // 0,32
    const int mr = lane & 15;
    const int q4 = lane >> 4;

    const int row_a = t >> 2;                       // 0..63
    const int seg   = ((t & 3) ^ ((t >> 3) & 3)) * 8;
    const int csw   = (q4 ^ ((mr >> 1) & 3)) * 16;

    f32x4 acc[4][2] = {};

    for (int k0 = 0; k0 < K; k0 += 32) {
        __syncthreads();
        gld_lds16(A + (size_t)(m0 + row_a) * lda + k0 + seg,      (char*)lA + wid * 1024);
        gld_lds16(A + (size_t)(m0 + 64 + row_a) * lda + k0 + seg, (char*)lA + 4096 + wid * 1024);
        gld_lds16(B + (size_t)(n0 + row_a) * ldb + k0 + seg,      (char*)lB + wid * 1024);
        __syncthreads();

        bf16x8 af[4], bf[2];
#pragma unroll
        for (int i = 0; i < 4; ++i)
            af[i] = *(const bf16x8*)((const char*)lA + (wm + i * 16 + mr) * 64 + csw);
#pragma unroll
        for (int j = 0; j < 2; ++j)
            bf[j] = *(const bf16x8*)((const char*)lB + (wn + j * 16 + mr) * 64 + csw);
#pragma unroll
        for (int i = 0; i < 4; ++i)
#pragma unroll
            for (int j = 0; j < 2; ++j)
                acc[i][j] = __builtin_amdgcn_mfma_f32_16x16x32_bf16(af[i], bf[j], acc[i][j], 0, 0, 0);
    }

    OutT* Cw = C0 + (size_t)z * strideC0;
#pragma unroll
    for (int i = 0; i < 4; ++i) {
        const int rbase = m0 + wm + i * 16 + q4 * 4;
#pragma unroll
        for (int j = 0; j < 2; ++j) {
            const int col = n0 + wn + j * 16 + mr;
#pragma unroll
            for (int r = 0; r < 4; ++r) {
                const float v = acc[i][j][r];
                const size_t off = (size_t)(rbase + r) * ldc0 + col;
                if constexpr (sizeof(OutT) == 2) Cw[off] = f2bf(v);
                else                             Cw[off] = v;
            }
        }
    }
}

// ---------------------------------------------------------------------------
// C = A @ B^T, fp32 out. 256x256 tile, BK=64, 8-phase schedule.
// R8: ds_reads issued one phase AHEAD (between lgkmcnt(0) and MFMA of the
// previous phase), so every lgkmcnt(0) waits on ~600-cycle-old reads.
// aA double-set (aX/aY); bB single set, reloaded for kt+1 at p3 after the
// vmcnt checkpoint (kt+1 guaranteed landed). Epilogue: acc -> LDS (2 passes
// of 128KiB) -> global_store_dwordx4 fully coalesced.
// Stage stream unchanged: prologue kt0{B0,B1,A0,A1}+kt1{B0,B1,A0}, vmcnt(6);
// p0:(kt+1).A1  p1:(kt+2).B0  p2:(kt+2).B1  p3:(kt+2).A0; vmcnt(6) at p3
// leaves exactly {B0,B1,A0}(kt+2) in flight; vmcnt(0) at kt==NT-2.
// ---------------------------------------------------------------------------
__global__ __launch_bounds__(512, 2)
void gemm256_bt(const ushort_t* __restrict__ A, int lda, long strideA,
                const ushort_t* __restrict__ B, int ldb, long strideB,
                float* __restrict__ C, int ldc, long strideC, int K)
{
    __shared__ char lds[131072];

    const int t    = threadIdx.x;
    const int lane = t & 63;
    const int wid  = t >> 6;       // 0..7
    const int z    = blockIdx.z;

    A += (size_t)z * strideA;
    B += (size_t)z * strideB;

    const int m0 = blockIdx.x * 256;
    const int n0 = blockIdx.y * 256;

    const int wm = wid >> 2;       // 0..1  (row half)
    const int wn = wid & 3;        // 0..3  (64-col slice)
    const int mr = lane & 15;
    const int q4 = lane >> 4;      // 0..3
    const int cb = (wn & 1) << 6;

    const int NT = K >> 6;         // 64-wide K-tiles

    // staging: physical chunk = t*16 within 8KB half; inverse-swizzled source
    const int srow = t >> 3;                                    // 0..63
    const int scol = ((t & 7) << 3) ^ (((t >> 3) & 7) << 3);    // elements

    auto stage_half = [&](const ushort_t* __restrict__ src, int ld, int org,
                          int h, int tgt, int bsel) {
        if (tgt >= NT) return;
        char* base = lds + bsel + ((tgt & 1) << 15) + (h << 14) + wid * 1024;
        const ushort_t* g = src + (size_t)(org + h * 128 + srow) * ld + tgt * 64 + scol;
        gld_lds16(g, base);                            // rows 0..63 of half
        gld_lds16(g + ((size_t)ld << 6), base + 8192); // rows 64..127
    };
    // unit ids: 0=B.h0 1=B.h1 2=A.h0 3=A.h1
    auto stage_unit = [&](int u, int tgt) {
        if (u < 2) stage_half(B, ldb, n0, u,     tgt, 65536);
        else       stage_half(A, lda, m0, u - 2, tgt, 0);
    };

    bf16x8 aX[2][2], aY[2][2], bB[4][2];

    auto rdA = [&](bf16x8 (&dst)[2][2], const char* aBuf, int p) {
#pragma unroll
        for (int s = 0; s < 2; ++s) {
            const int lr = (2 * p + s) * 16 + mr;
            const int kx = (lr & 7) << 4;
#pragma unroll
            for (int ks = 0; ks < 2; ++ks)
                dst[s][ks] = *(const bf16x8*)(aBuf + lr * 128 + ((ks * 64 + q4 * 16) ^ kx));
        }
    };
    auto rdB = [&](const char* bBuf) {
#pragma unroll
        for (int j = 0; j < 4; ++j) {
            const int c  = cb + j * 16 + mr;
            const int kx = (c & 7) << 4;
#pragma unroll
            for (int ks = 0; ks < 2; ++ks)
                bB[j][ks] = *(const bf16x8*)(bBuf + c * 128 + ((ks * 64 + q4 * 16) ^ kx));
        }
    };

    f32x4 acc[8][4] = {};
    auto MM = [&](int p, bf16x8 (&a)[2][2]) {
        __builtin_amdgcn_s_setprio(1);
#pragma unroll
        for (int s = 0; s < 2; ++s)
#pragma unroll
            for (int j = 0; j < 4; ++j)
#pragma unroll
                for (int ks = 0; ks < 2; ++ks)
                    acc[2 * p + s][j] = __builtin_amdgcn_mfma_f32_16x16x32_bf16(
                        a[s][ks], bB[j][ks], acc[2 * p + s][j], 0, 0, 0);
        __builtin_amdgcn_s_setprio(0);
    };

#define BAR()  __builtin_amdgcn_s_barrier()
#define SB()   __builtin_amdgcn_sched_barrier(0)
#define LGKM0() asm volatile("s_waitcnt lgkmcnt(0)" ::: "memory")

    // --- prologue: kt0 full + kt1 {B0,B1,A0}; keep 3 units in flight
    stage_unit(0, 0); stage_unit(1, 0); stage_unit(2, 0); stage_unit(3, 0);
    stage_unit(0, 1); stage_unit(1, 1); stage_unit(2, 1);
    asm volatile("s_waitcnt vmcnt(6)" ::: "memory");
    BAR();

    // pre-load kt0 p0 registers
    {
        const char* a0 = lds + (wm << 14);
        const char* b0 = lds + 65536 + ((wn >> 1) << 14);
        rdA(aX, a0, 0);
        rdB(b0);
        SB();
    }

    for (int kt = 0; kt < NT; ++kt) {
        const char* aBuf  = lds + ((kt & 1) << 15) + (wm << 14);
        const char* aBufN = lds + (((kt + 1) & 1) << 15) + (wm << 14);
        const char* bBufN = lds + 65536 + (((kt + 1) & 1) << 15) + ((wn >> 1) << 14);

        // ---- p0 ----  (uses aX, loaded at prev p3 / pre-loop)
        stage_unit(3, kt + 1);
        BAR(); LGKM0(); SB();
        rdA(aY, aBuf, 1); SB();          // p1 regs, hidden under p0 MFMA
        MM(0, aX); SB();
        BAR();
        // ---- p1 ----
        stage_unit(0, kt + 2);
        BAR(); LGKM0(); SB();
        rdA(aX, aBuf, 2); SB();
        MM(1, aY); SB();
        BAR();
        // ---- p2 ----
        stage_unit(1, kt + 2);
        BAR(); LGKM0(); SB();
        rdA(aY, aBuf, 3); SB();
        MM(2, aX); SB();
        BAR();
        // ---- p3 ----
        stage_unit(2, kt + 2);
        BAR(); LGKM0(); SB();
        MM(3, aY); SB();
        if (kt == NT - 2)     asm volatile("s_waitcnt vmcnt(0)" ::: "memory");
        else if (kt < NT - 2) asm volatile("s_waitcnt vmcnt(6)" ::: "memory");
        if (kt + 1 < NT) {               // next-kt p0 regs (kt+1 fully landed)
            rdA(aX, aBufN, 0);
            rdB(bBufN);
            SB();
        }
        BAR();
    }

#undef BAR
#undef SB
#undef LGKM0

    // --- epilogue: acc -> LDS -> coalesced dwordx4 stores (2 passes) ---
    float* Cw = C + (size_t)z * strideC;
    float* sf = (float*)lds;
#pragma unroll
    for (int h = 0; h < 2; ++h) {
        if (h) __syncthreads();
#pragma unroll
        for (int i2 = 0; i2 < 4; ++i2) {
            const int rl = wm * 64 + i2 * 16 + q4 * 4;
#pragma unroll
            for (int j = 0; j < 4; ++j) {
                const int cl = wn * 64 + j * 16 + mr;
#pragma unroll
                for (int r = 0; r < 4; ++r)
                    sf[(rl + r) * 256 + cl] = acc[h * 4 + i2][j][r];
            }
        }
        __syncthreads();
#pragma unroll
        for (int k = 0; k < 16; ++k) {
            const int rl   = k * 8 + wid;
            const int grow = m0 + (rl >> 6) * 128 + h * 64 + (rl & 63);
            const f32x4 v  = *(const f32x4*)&sf[rl * 256 + lane * 4];
            *(f32x4*)&Cw[(size_t)grow * ldc + n0 + lane * 4] = v;
        }
    }
}

// ---------------------------------------------------------------------------
// Gram GEMM: Gp[z] partial of x[b]^T x[b], upper-triangle 128-tiles only.
// grid (16 z fastest -> XCD round-robin, 36 triangle tiles). A = B = xbT.
// z = b*4+ks: columns b*4096 + ks*1024 of xbT [1024][16384].
// ---------------------------------------------------------------------------
__global__ __launch_bounds__(256, 2)
void gemm_gram(const ushort_t* __restrict__ X, ushort_t* __restrict__ Gp)
{
    __shared__ ushort_t lA[128 * 32];
    __shared__ ushort_t lB[128 * 32];

    const int t    = threadIdx.x;
    const int lane = t & 63;
    const int wid  = t >> 6;

    const int z  = blockIdx.x;
    const int bb = z >> 2, ks = z & 3;

    // triangle tile map: row ti has 8-ti tiles (ti<=tj)
    int ti = 0, rem = blockIdx.y;
    while (rem >= 8 - ti) { rem -= 8 - ti; ++ti; }
    const int tj = ti + rem;
    const int m0 = ti * 128;
    const int n0 = tj * 128;

    const ushort_t* A = X + (size_t)bb * 4096 + (size_t)ks * 1024;

    const int wm = (wid >> 1) * 64;
    const int wn = (wid & 1) * 64;
    const int mr = lane & 15;
    const int q4 = lane >> 4;

    const int row_a = t >> 2;
    const int seg   = ((t & 3) ^ ((t >> 3) & 3)) * 8;
    const int csw   = (q4 ^ ((mr >> 1) & 3)) * 16;

    f32x4 acc[4][4] = {};

    for (int k0 = 0; k0 < 1024; k0 += 32) {
        __syncthreads();
        gld_lds16(A + (size_t)(m0 + row_a) * 16384 + k0 + seg,      (char*)lA + wid * 1024);
        gld_lds16(A + (size_t)(m0 + 64 + row_a) * 16384 + k0 + seg, (char*)lA + 4096 + wid * 1024);
        gld_lds16(A + (size_t)(n0 + row_a) * 16384 + k0 + seg,      (char*)lB + wid * 1024);
        gld_lds16(A + (size_t)(n0 + 64 + row_a) * 16384 + k0 + seg, (char*)lB + 4096 + wid * 1024);
        __syncthreads();

        bf16x8 af[4], bf[4];
#pragma unroll
        for (int i = 0; i < 4; ++i)
            af[i] = *(const bf16x8*)((const char*)lA + (wm + i * 16 + mr) * 64 + csw);
#pragma unroll
        for (int j = 0; j < 4; ++j)
            bf[j] = *(const bf16x8*)((const char*)lB + (wn + j * 16 + mr) * 64 + csw);
#pragma unroll
        for (int i = 0; i < 4; ++i)
#pragma unroll
            for (int j = 0; j < 4; ++j)
                acc[i][j] = __builtin_amdgcn_mfma_f32_16x16x32_bf16(af[i], bf[j], acc[i][j], 0, 0, 0);
    }

    ushort_t* Cw = Gp + ((size_t)z << 20);
#pragma unroll
    for (int i = 0; i < 4; ++i) {
        const int rbase = m0 + wm + i * 16 + q4 * 4;
#pragma unroll
        for (int j = 0; j < 4; ++j) {
            const int col = n0 + wn + j * 16 + mr;
#pragma unroll
            for (int r = 0; r < 4; ++r)
                Cw[(size_t)(rbase + r) * 1024 + col] = f2bf(acc[i][j][r]);
        }
    }
}

// ---------------------------------------------------------------------------
// reduce_g_t: G[b][tr*64+r][tc*64+c] = sum_ks Gp[b*4+ks] at source 64-tile
// (sr,sc)=(min,max) -- inside computed upper 128-triangle since
// sr<=sc => sr>>1 <= sc>>1. Lower tiles transpose through LDS (pitch 65).
// grid (256 tiles: tr=bx>>4, tc=bx&15; 4 b), 256 threads.
// ---------------------------------------------------------------------------
__global__ __launch_bounds__(256)
void reduce_g_t(const ushort_t* __restrict__ Gp, ushort_t* __restrict__ G)
{
    __shared__ float acc[64 * 65];

    const int t  = threadIdx.x;
    const int b  = blockIdx.y;
    const int tr = blockIdx.x >> 4, tc = blockIdx.x & 15;
    const int sr = (tr <= tc) ? tr : tc;
    const int sc = (tr <= tc) ? tc : tr;
    const bool flip = tr > tc;

#pragma unroll
    for (int p = 0; p < 4; ++p) {
        const int idx = p * 256 + t;             // ushort4 index 0..1023
        const int r = idx >> 4, c = (idx & 15) * 4;
        float a0 = 0.f, a1 = 0.f, a2 = 0.f, a3 = 0.f;
#pragma unroll
        for (int ksl = 0; ksl < 4; ++ksl) {
            const ushort4 u = *(const ushort4*)&Gp[((size_t)(b * 4 + ksl) << 20)
                                                   + (size_t)(sr * 64 + r) * 1024 + sc * 64 + c];
            a0 += bf2f(u.x); a1 += bf2f(u.y); a2 += bf2f(u.z); a3 += bf2f(u.w);
        }
        acc[r * 65 + c + 0] = a0;
        acc[r * 65 + c + 1] = a1;
        acc[r * 65 + c + 2] = a2;
        acc[r * 65 + c + 3] = a3;
    }
    __syncthreads();

#pragma unroll
    for (int p = 0; p < 4; ++p) {
        const int idx = p * 256 + t;
        const int r = idx >> 4, c = (idx & 15) * 4;
        float v0, v1, v2, v3;
        if (flip) {
            v0 = acc[(c + 0) * 65 + r];
            v1 = acc[(c + 1) * 65 + r];
            v2 = acc[(c + 2) * 65 + r];
            v3 = acc[(c + 3) * 65 + r];
        } else {
            v0 = acc[r * 65 + c + 0];
            v1 = acc[r * 65 + c + 1];
            v2 = acc[r * 65 + c + 2];
            v3 = acc[r * 65 + c + 3];
        }
        ushort4 o;
        o.x = f2bf(v0); o.y = f2bf(v1); o.z = f2bf(v2); o.w = f2bf(v3);
        *(ushort4*)&G[((size_t)b << 20) + (size_t)(tr * 64 + r) * 1024 + tc * 64 + c] = o;
    }
}

// ---------------------------------------------------------------------------
// cast x fp32 [16384][1024] -> xb bf16 + xbT bf16 [1024][16384]
// ---------------------------------------------------------------------------
__global__ __launch_bounds__(256)
void cast_x_t(const float* __restrict__ x, ushort_t* __restrict__ xb,
              ushort_t* __restrict__ xbT)
{
    __shared__ ushort_t lt[64 * 66];
    const int t  = threadIdx.x;
    const int s0 = blockIdx.x * 64;
    const int i0 = blockIdx.y * 64;

#pragma unroll
    for (int c = 0; c < 4; ++c) {
        const int idx = c * 256 + t;
        const int r = idx >> 4, c4 = (idx & 15) * 4;
        const float4 f = *(const float4*)&x[(size_t)(s0 + r) * 1024 + i0 + c4];
        ushort4 o;
        o.x = f2bf(f.x); o.y = f2bf(f.y); o.z = f2bf(f.z); o.w = f2bf(f.w);
        *(ushort4*)&xb[(size_t)(s0 + r) * 1024 + i0 + c4] = o;
        *(uint32_t*)&lt[r * 66 + c4]     = (uint32_t)o.x | ((uint32_t)o.y << 16);
        *(uint32_t*)&lt[r * 66 + c4 + 2] = (uint32_t)o.z | ((uint32_t)o.w << 16);
    }
    __syncthreads();
#pragma unroll
    for (int c = 0; c < 4; ++c) {
        const int idx = c * 256 + t;
        const int ri = idx >> 4, s4 = (idx & 15) * 4;
        ushort4 o;
        o.x = lt[(s4 + 0) * 66 + ri];
        o.y = lt[(s4 + 1) * 66 + ri];
        o.z = lt[(s4 + 2) * 66 + ri];
        o.w = lt[(s4 + 3) * 66 + ri];
        *(ushort4*)&xbT[(size_t)(i0 + ri) * 16384 + s0 + s4] = o;
    }
}

// ---------------------------------------------------------------------------
// cast+transpose Wq fp32 -> wqT bf16
// ---------------------------------------------------------------------------
__global__ __launch_bounds__(256)
void cast_wt(const float* __restrict__ W, ushort_t* __restrict__ WT)
{
    __shared__ ushort_t lt[64 * 66];
    const int t  = threadIdx.x;
    const int r0 = blockIdx.x * 64;
    const int c0 = blockIdx.y * 64;

#pragma unroll
    for (int c = 0; c < 4; ++c) {
        const int idx = c * 256 + t;
        const int r = idx >> 4, c4 = (idx & 15) * 4;
        const float4 f = *(const float4*)&W[(size_t)(r0 + r) * 1024 + c0 + c4];
        ushort4 o;
        o.x = f2bf(f.x); o.y = f2bf(f.y); o.z = f2bf(f.z); o.w = f2bf(f.w);
        *(uint32_t*)&lt[r * 66 + c4]     = (uint32_t)o.x | ((uint32_t)o.y << 16);
        *(uint32_t*)&lt[r * 66 + c4 + 2] = (uint32_t)o.z | ((uint32_t)o.w << 16);
    }
    __syncthreads();
#pragma unroll
    for (int c = 0; c < 4; ++c) {
        const int idx = c * 256 + t;
        const int ri = idx >> 4, s4 = (idx & 15) * 4;
        ushort4 o;
        o.x = lt[(s4 + 0) * 66 + ri];
        o.y = lt[(s4 + 1) * 66 + ri];
        o.z = lt[(s4 + 2) * 66 + ri];
        o.w = lt[(s4 + 3) * 66 + ri];
        *(ushort4*)&WT[(size_t)(c0 + ri) * 1024 + r0 + s4] = o;
    }
}

// ---------------------------------------------------------------------------
// plain cast Wk/Wv fp32 -> bf16
// ---------------------------------------------------------------------------
__global__ __launch_bounds__(256)
void cast_w2(const float* __restrict__ a, const float* __restrict__ b,
             ushort_t* __restrict__ out)
{
    const float* src = (blockIdx.y == 0) ? a : b;
    const int i = (blockIdx.x * 256 + threadIdx.x) * 4;
    const float4 f = *(const float4*)&src[i];
    ushort4 o;
    o.x = f2bf(f.x); o.y = f2bf(f.y); o.z = f2bf(f.z); o.w = f2bf(f.w);
    *(ushort4*)&out[(size_t)blockIdx.y * 1048576 + i] = o;
}

// ---------------------------------------------------------------------------
// kv partials: KVp[is][bh][d][e] = sum_{i-slice} H[b][h64+d][i]*Wv[h64+e][i]
// ---------------------------------------------------------------------------
__global__ __launch_bounds__(256)
void kvblk(const ushort_t* __restrict__ H, const ushort_t* __restrict__ Wv,
           float* __restrict__ KVp)
{
    __shared__ ushort_t sH[64 * 132];
    __shared__ ushort_t sV[64 * 132];

    const int t  = threadIdx.x;
    const int is = blockIdx.x;
    const int bh = blockIdx.y;
    const int b  = bh >> 4, h = bh & 15;

    const ushort_t* Hp = H + ((size_t)b << 20) + (size_t)(h * 64) * 1024 + is * 128;
    const ushort_t* Vp = Wv + (size_t)(h * 64) * 1024 + is * 128;

#pragma unroll
    for (int i2 = 0; i2 < 8; ++i2) {
        const int ci = i2 * 256 + t;
        const int r = ci >> 5, c = (ci & 31) * 4;
        *(uint2*)&sH[r * 132 + c] = *(const uint2*)&Hp[(size_t)r * 1024 + c];
        *(uint2*)&sV[r * 132 + c] = *(const uint2*)&Vp[(size_t)r * 1024 + c];
    }
    __syncthreads();

    const int d0 = (t >> 4) * 4;
    const int e0 = (t & 15) * 4;
    float acc[4][4] = {};

#pragma unroll 2
    for (int i4 = 0; i4 < 128; i4 += 4) {
        uint2 hu[4], vu[4];
#pragma unroll
        for (int j = 0; j < 4; ++j) {
            hu[j] = *(const uint2*)&sH[(d0 + j) * 132 + i4];
            vu[j] = *(const uint2*)&sV[(e0 + j) * 132 + i4];
        }
        float hf[4][4], vf[4][4];
#pragma unroll
        for (int j = 0; j < 4; ++j) {
            hf[j][0] = __uint_as_float(hu[j].x << 16);
            hf[j][1] = __uint_as_float(hu[j].x & 0xffff0000u);
            hf[j][2] = __uint_as_float(hu[j].y << 16);
            hf[j][3] = __uint_as_float(hu[j].y & 0xffff0000u);
            vf[j][0] = __uint_as_float(vu[j].x << 16);
            vf[j][1] = __uint_as_float(vu[j].x & 0xffff0000u);
            vf[j][2] = __uint_as_float(vu[j].y << 16);
            vf[j][3] = __uint_as_float(vu[j].y & 0xffff0000u);
        }
#pragma unroll
        for (int ii = 0; ii < 4; ++ii)
#pragma unroll
            for (int di = 0; di < 4; ++di)
#pragma unroll
                for (int ej = 0; ej < 4; ++ej)
                    acc[di][ej] += hf[di][ii] * vf[ej][ii];
    }

    float* outp = KVp + ((size_t)(is * 64 + bh)) * 4096;
#pragma unroll
    for (int i = 0; i < 4; ++i) {
        float4 o; o.x = acc[i][0]; o.y = acc[i][1]; o.z = acc[i][2]; o.w = acc[i][3];
        *(float4*)&outp[(d0 + i) * 64 + e0] = o;
    }
}

// ---------------------------------------------------------------------------
__global__ __launch_bounds__(256)
void reduce_kv8(const float4* __restrict__ in, float4* __restrict__ out)
{
    const int i = blockIdx.x * 256 + threadIdx.x;
    float4 a = in[i];
#pragma unroll
    for (int s = 1; s < 8; ++s) {
        const float4 b = in[s * 65536 + i];
        a.x += b.x; a.y += b.y; a.z += b.z; a.w += b.w;
    }
    out[i] = a;
}

// ---------------------------------------------------------------------------
// E_t[b][j][h*64+d] = scale * sum_e kv[b,h,d,e] * W_o[j, h*64+e]
// ---------------------------------------------------------------------------
__global__ __launch_bounds__(256)
void make_E(const float* __restrict__ KV, const float* __restrict__ Wo,
            ushort_t* __restrict__ Et)
{
    __shared__ float skv[64 * 65];
    __shared__ float swo[64 * 65];

    const int t  = threadIdx.x;
    const int bh = blockIdx.y;
    const int b  = bh >> 4, h = bh & 15;
    const int j0 = blockIdx.x * 64;

    const float* kvp = KV + (size_t)bh * 4096;
#pragma unroll
    for (int i = 0; i < 4; ++i) {
        const int idx = t + i * 256;
        const int r = idx >> 4, c = (idx & 15) * 4;
        const float4 f = *(const float4*)&kvp[r * 64 + c];
        skv[r * 65 + c + 0] = f.x;
        skv[r * 65 + c + 1] = f.y;
        skv[r * 65 + c + 2] = f.z;
        skv[r * 65 + c + 3] = f.w;
        const float4 g = *(const float4*)&Wo[(size_t)(j0 + r) * 1024 + h * 64 + c];
        swo[r * 65 + c + 0] = g.x;
        swo[r * 65 + c + 1] = g.y;
        swo[r * 65 + c + 2] = g.z;
        swo[r * 65 + c + 3] = g.w;
    }
    __syncthreads();

    const int d0 = (t & 15) * 4;
#pragma unroll
    for (int pass = 0; pass < 4; ++pass) {
        const int jloc = (t >> 4) + pass * 16;
        float s0 = 0.f, s1 = 0.f, s2 = 0.f, s3 = 0.f;
        const float* wrow = &swo[jloc * 65];
#pragma unroll 8
        for (int e = 0; e < 64; ++e) {
            const float w = wrow[e];
            s0 += skv[(d0 + 0) * 65 + e] * w;
            s1 += skv[(d0 + 1) * 65 + e] * w;
            s2 += skv[(d0 + 2) * 65 + e] * w;
            s3 += skv[(d0 + 3) * 65 + e] * w;
        }
        ushort4 o;
        o.x = f2bf(s0 * 0.125f);
        o.y = f2bf(s1 * 0.125f);
        o.z = f2bf(s2 * 0.125f);
        o.w = f2bf(s3 * 0.125f);
        *(ushort4*)&Et[((size_t)b * 1024 + j0 + jloc) * 1024 + h * 64 + d0] = o;
    }
}

// ---------------------------------------------------------------------------

extern "C" void kernel_launch(void* const* d_in, const int* in_sizes, int n_in,
                              void* d_out, int out_size, void* d_ws, size_t ws_size,
                              hipStream_t stream)
{
    const float* x  = (const float*)d_in[0];
    const float* Wq = (const float*)d_in[1];
    const float* Wk = (const float*)d_in[2];
    const float* Wv = (const float*)d_in[3];
    const float* Wo = (const float*)d_in[4];
    float* out = (float*)d_out;

    const int B = 4, S = 4096, D = 1024;
    const long MB1 = 1048576;

    char* ws = (char*)d_ws;
    size_t off = 0;
    auto alloc = [&](size_t bytes) -> void* {
        void* p = ws + off;
        off += (bytes + 255) & ~(size_t)255;
        return p;
    };
    ushort_t* xb   = (ushort_t*)alloc((size_t)B * S * D * 2);      // 33.5 MB
    ushort_t* xbT  = (ushort_t*)alloc((size_t)D * B * S * 2);      // 33.5 MB
    ushort_t* wkv  = (ushort_t*)alloc((size_t)2 * D * D * 2);      // wk | wv
    ushort_t* wqT  = (ushort_t*)alloc((size_t)D * D * 2);
    ushort_t* Gb   = (ushort_t*)alloc((size_t)B * D * D * 2);      // 8.4 MB
    float*    kvp  = (float*)alloc((size_t)8 * 64 * 4096 * 4);     // 8.4 MB
    float*    kvr  = (float*)alloc((size_t)64 * 4096 * 4);         // 1 MB
    ushort_t* Fb   = (ushort_t*)alloc((size_t)B * D * D * 2);      // 8.4 MB (own slab!)
    char*     R1   = (char*)alloc((size_t)16 * MB1 * 2);           // 33.5 MB shared
    ushort_t* Gp = (ushort_t*)R1;                    // [16][1M] bf16 partials
    ushort_t* Hb = (ushort_t*)R1;                    // [4][1M] (Gp[0..7] dead after reduce)
    ushort_t* Et = (ushort_t*)(R1 + 8 * MB1 * 2);    // [4][1M] (Gp[8..15] dead after reduce)
    ushort_t* wkb = wkv;
    ushort_t* wvb = wkv + MB1;

    // casts
    cast_x_t<<<dim3(256, 16), dim3(256), 0, stream>>>(x, xb, xbT);
    cast_w2<<<dim3(1024, 2), dim3(256), 0, stream>>>(Wk, Wv, wkv);
    cast_wt<<<dim3(16, 16), dim3(256), 0, stream>>>(Wq, wqT);

    // G[b] = x^T x, symmetric: 36 upper-triangle 128-tiles, split-K=4, z fastest
    gemm_gram<<<dim3(16, 36), dim3(256), 0, stream>>>(xbT, Gp);
    reduce_g_t<<<dim3(256, 4), dim3(256), 0, stream>>>(Gp, Gb);

    // H[b] = Wk @ G[b]  (G symmetric -> use as B directly); 512 blocks, 2/CU
    gemm_bt_n64<ushort_t><<<dim3(8, 16, 4), dim3(256), 0, stream>>>(
        wkb, D, 0, Gb, D, MB1, Hb, D, MB1, D);

    // kv[b,h] = H_h @ Wv_h^T (i-split 8) + reduce
    kvblk<<<dim3(8, 64), dim3(256), 0, stream>>>(Hb, wvb, kvp);
    reduce_kv8<<<dim3(256), dim3(256), 0, stream>>>((const float4*)kvp, (float4*)kvr);

    // E_t
    make_E<<<dim3(16, 64), dim3(256), 0, stream>>>(kvr, Wo, Et);

    // F[b] = E_t[b] @ Wq; 512 blocks, 2/CU
    gemm_bt_n64<ushort_t><<<dim3(8, 16, 4), dim3(256), 0, stream>>>(
        Et, D, MB1, wqT, D, 0, Fb, D, (long)D * D, D);

    // out[b] = x[b] @ F[b]^T -> fp32, 256^2 8-phase (R8: reg-prefetch + LDS epi)
    gemm256_bt<<<dim3(16, 4, 4), dim3(512), 0, stream>>>(
        xb, D, (long)S * D, Fb, D, (long)D * D, out, D, (long)S * D, D);
}